// Round 12
// baseline (350.972 us; speedup 1.0000x reference)
//
#include <hip/hip_runtime.h>

static constexpr int NN   = 100000;
static constexpr int NE   = 2400000;
static constexpr int MSH  = 9;                     // mid bucket shift (512 nodes)
static constexpr unsigned MMSK = 511;
static constexpr int NND  = 512;                   // nodes per mid bucket
static constexpr int MBN  = (NN + NND - 1) / NND;  // 196 mid buckets
static constexpr int CAPM = 13184;                 // per-mid capacity (mean 12245 + ~8.5 sigma)
static constexpr int NPB  = 512;                   // partition blocks
static constexpr int SEG  = 4688;                  // edges per partition block (last ragged)
static constexpr int NAB  = MBN * 4;               // aggregation blocks (quarter-bucket)
static_assert((size_t)NPB * SEG >= NE, "segments cover edge list");
static_assert(MBN <= 256, "sbkt uint8 + 256-wide scan");
static_assert((NN * 16) % 256 == 0, "klin grids exact");

// zero {deg, acc1, acc3, acc2} (NN*19 words) + init mid cursors
__global__ __launch_bounds__(256) void kzero(uint4* __restrict__ z,
                                             unsigned* __restrict__ cursorA) {
    unsigned i = blockIdx.x * 256 + threadIdx.x;
    constexpr unsigned NQ = (unsigned)NN * 19u / 4u;
    if (i < NQ) { uint4 v; v.x = v.y = v.z = v.w = 0u; z[i] = v; }
    if (i < MBN) cursorA[i] = i * (unsigned)CAPM;
}

// pass 1: LDS counting-sort into 196 mid buckets + atomic space reservation +
// coalesced drain (runs ~24 = 96B)
__global__ __launch_bounds__(256) void kpartA(const int* __restrict__ src,
                                              const int* __restrict__ dst,
                                              unsigned* __restrict__ cursorA,
                                              unsigned* __restrict__ csr) {
    __shared__ unsigned scode[SEG];
    __shared__ unsigned char sbkt[SEG];
    __shared__ unsigned hist[MBN], gb[MBN], ex[MBN];
    __shared__ unsigned sc1[256], sc2[256];
    int b = blockIdx.x, t = threadIdx.x;
    for (int k = t; k < MBN; k += 256) hist[k] = 0;
    __syncthreads();
    int off = b * SEG;
    int n = NE - off; if (n > SEG) n = SEG; if (n < 0) n = 0;
    for (int j = t; j < n; j += 256)
        atomicAdd(&hist[(unsigned)dst[off + j] >> MSH], 1u);
    __syncthreads();
    unsigned hv = (t < MBN) ? hist[t] : 0u;
    sc1[t] = hv;
    __syncthreads();
    unsigned* cu = sc1; unsigned* nx = sc2;
    for (int o = 1; o < 256; o <<= 1) {
        unsigned v = cu[t];
        if (t >= o) v += cu[t - o];
        nx[t] = v;
        __syncthreads();
        unsigned* tm = cu; cu = nx; nx = tm;
    }
    if (t < MBN) {
        ex[t] = cu[t] - hv;
        gb[t] = hv ? atomicAdd(&cursorA[t], hv) : 0u;   // reserve global space
    }
    __syncthreads();
    if (t < MBN) hist[t] = ex[t];      // reuse as LDS scatter cursor
    __syncthreads();
    for (int j = t; j < n; j += 256) {
        unsigned d = (unsigned)dst[off + j], s = (unsigned)src[off + j];
        unsigned bk = d >> MSH;
        unsigned p = atomicAdd(&hist[bk], 1u);
        scode[p] = (s << MSH) | (d & MMSK);
        sbkt[p] = (unsigned char)bk;
    }
    __syncthreads();
    for (int i = t; i < n; i += 256) {
        unsigned bk = sbkt[i];
        unsigned dest = gb[bk] + ((unsigned)i - ex[bk]);
        if (dest < (bk + 1u) * CAPM) csr[dest] = scode[i];   // overflow guard
    }
}

// degree scatter: quarter-bucket per block, LDS int counts, partial-add global
__global__ __launch_bounds__(256) void kdeg(const unsigned* __restrict__ csr,
                                            const unsigned* __restrict__ cursorA,
                                            int* __restrict__ deg) {
    __shared__ int icnt[NND];
    int b = blockIdx.x, t = threadIdx.x;
    unsigned m = (unsigned)b >> 2, q = (unsigned)b & 3;
    unsigned base = m * (unsigned)CAPM;
    unsigned nM = cursorA[m] - base; if (nM > CAPM) nM = CAPM;
    unsigned j0 = (nM * q) >> 2, j1 = (nM * (q + 1)) >> 2;
    icnt[t] = 0; icnt[t + 256] = 0;
    __syncthreads();
    for (unsigned j = j0 + t; j < j1; j += 256)
        atomicAdd(&icnt[csr[base + j] & MMSK], 1);
    __syncthreads();
    for (int l = t; l < NND; l += 256) {
        int node = (int)(m * NND) + l;
        int v = icnt[l];
        if (node < NN && v) atomicAdd(&deg[node], v);
    }
}

// dis = rsqrt(deg+1);  y1 = dis * x
__global__ __launch_bounds__(256) void kdisy1(const int* __restrict__ deg,
                                              const float* __restrict__ x,
                                              float* __restrict__ dis,
                                              float* __restrict__ y1) {
    int i = blockIdx.x * 256 + threadIdx.x;
    if (i < NN) {
        float d = rsqrtf((float)(deg[i] + 1));
        dis[i] = d;
        y1[i] = d * x[i];
    }
}

// scalar scatter aggregate: quarter-bucket per block
__global__ __launch_bounds__(256) void kaggs(const unsigned* __restrict__ csr,
                                             const unsigned* __restrict__ cursorA,
                                             const float* __restrict__ y,
                                             float* __restrict__ acc) {
    __shared__ float facc[NND];
    int b = blockIdx.x, t = threadIdx.x;
    unsigned m = (unsigned)b >> 2, q = (unsigned)b & 3;
    unsigned base = m * (unsigned)CAPM;
    unsigned nM = cursorA[m] - base; if (nM > CAPM) nM = CAPM;
    unsigned j0 = (nM * q) >> 2, j1 = (nM * (q + 1)) >> 2;
    facc[t] = 0.f; facc[t + 256] = 0.f;
    __syncthreads();
    for (unsigned j = j0 + t; j < j1; j += 256) {
        unsigned c = csr[base + j];
        atomicAdd(&facc[c & MMSK], y[c >> MSH]);
    }
    __syncthreads();
    for (int l = t; l < NND; l += 256) {
        int node = (int)(m * NND) + l;
        float v = facc[l];
        if (node < NN && v != 0.f) atomicAdd(&acc[node], v);
    }
}

// 16-wide scatter aggregate: 16 lanes per edge (parallel LDS atomics), 32KB LDS
__global__ __launch_bounds__(256) void kagg16s(const unsigned* __restrict__ csr,
                                               const unsigned* __restrict__ cursorA,
                                               const float* __restrict__ y2,
                                               float* __restrict__ acc2) {
    __shared__ float facc[NND * 16];
    int b = blockIdx.x, t = threadIdx.x;
    unsigned m = (unsigned)b >> 2, q = (unsigned)b & 3;
    unsigned base = m * (unsigned)CAPM;
    unsigned nM = cursorA[m] - base; if (nM > CAPM) nM = CAPM;
    unsigned j0 = (nM * q) >> 2, j1 = (nM * (q + 1)) >> 2;
    for (int i = t; i < NND * 16; i += 256) facc[i] = 0.f;
    __syncthreads();
    int g = t & 15, es = t >> 4;
    unsigned j = j0 + es;
    for (; j + 48 < j1; j += 64) {       // 4 independent chains in flight
        unsigned c0 = csr[base + j], c1 = csr[base + j + 16];
        unsigned c2 = csr[base + j + 32], c3 = csr[base + j + 48];
        float v0 = y2[(size_t)(c0 >> MSH) * 16 + g];
        float v1 = y2[(size_t)(c1 >> MSH) * 16 + g];
        float v2 = y2[(size_t)(c2 >> MSH) * 16 + g];
        float v3 = y2[(size_t)(c3 >> MSH) * 16 + g];
        atomicAdd(&facc[(c0 & MMSK) * 16 + g], v0);
        atomicAdd(&facc[(c1 & MMSK) * 16 + g], v1);
        atomicAdd(&facc[(c2 & MMSK) * 16 + g], v2);
        atomicAdd(&facc[(c3 & MMSK) * 16 + g], v3);
    }
    for (; j < j1; j += 16) {
        unsigned c = csr[base + j];
        atomicAdd(&facc[(c & MMSK) * 16 + g], y2[(size_t)(c >> MSH) * 16 + g]);
    }
    __syncthreads();
    for (int i = t; i < NND * 16; i += 256) {
        int node = (int)(m * NND) + (i >> 4);
        float v = facc[i];
        if (node < NN && v != 0.f) atomicAdd(&acc2[(size_t)node * 16 + (i & 15)], v);
    }
}

// y2[i,g] = dis * ( relu( (dis*(acc1+y1)) * W1 + b1 ) @ W2 )[g]
__global__ __launch_bounds__(256) void klin12(const float* __restrict__ acc1,
                                              const float* __restrict__ y1,
                                              const float* __restrict__ dis,
                                              const float* __restrict__ W1,
                                              const float* __restrict__ b1,
                                              const float* __restrict__ W2,
                                              float* __restrict__ y2) {
    __shared__ float sW1[32], sb1[32], sW2[512];
    int t = threadIdx.x;
    if (t < 32) { sW1[t] = W1[t]; sb1[t] = b1[t]; }
    for (int i = t; i < 512; i += 256) sW2[i] = W2[i];
    __syncthreads();
    int tg = blockIdx.x * 256 + t;
    if (tg >= NN * 16) return;
    int i = tg >> 4, g = tg & 15;
    float d = dis[i];
    float a = d * (acc1[i] + y1[i]);
    float acc = 0.f;
#pragma unroll
    for (int f = 0; f < 32; ++f) {
        float h = fmaxf(a * sW1[f] + sb1[f], 0.f);
        acc += h * sW2[f * 16 + g];
    }
    y2[tg] = d * acc;
}

// y3[i] = dis * sum_g relu( dis*(acc2+y2) + b2 )[g] * W3[g]
__global__ __launch_bounds__(256) void klin3(const float* __restrict__ acc2,
                                             const float* __restrict__ y2,
                                             const float* __restrict__ dis,
                                             const float* __restrict__ b2,
                                             const float* __restrict__ W3,
                                             float* __restrict__ y3) {
    int tg = blockIdx.x * 256 + threadIdx.x;
    if (tg >= NN * 16) return;
    int i = tg >> 4, g = tg & 15;
    float d = dis[i];
    float a2 = d * (acc2[tg] + y2[tg]) + b2[g];
    float hg = fmaxf(a2, 0.f) * W3[g];
    hg += __shfl_xor(hg, 1, 16);
    hg += __shfl_xor(hg, 2, 16);
    hg += __shfl_xor(hg, 4, 16);
    hg += __shfl_xor(hg, 8, 16);
    if (g == 0) y3[i] = d * hg;
}

// out[i] = dis*(acc3 + y3) + b3
__global__ __launch_bounds__(256) void kout(const float* __restrict__ acc3,
                                            const float* __restrict__ y3,
                                            const float* __restrict__ dis,
                                            const float* __restrict__ b3,
                                            float* __restrict__ out) {
    int i = blockIdx.x * 256 + threadIdx.x;
    if (i < NN) out[i] = dis[i] * (acc3[i] + y3[i]) + b3[0];
}

extern "C" void kernel_launch(void* const* d_in, const int* in_sizes, int n_in,
                              void* d_out, int out_size, void* d_ws, size_t ws_size,
                              hipStream_t stream) {
    const float* x  = (const float*)d_in[0];
    const int*   ei = (const int*)d_in[1];
    const int* src = ei;
    const int* dst = ei + NE;
    const float* W1 = (const float*)d_in[2];
    const float* b1 = (const float*)d_in[3];
    const float* W2 = (const float*)d_in[4];
    const float* b2 = (const float*)d_in[5];
    const float* W3 = (const float*)d_in[6];
    const float* b3 = (const float*)d_in[7];
    float* out = (float*)d_out;

    auto align256 = [](size_t v) { return (v + 255) & ~(size_t)255; };
    char* w = (char*)d_ws;
    auto carve = [&](size_t bytes) { char* p = w; w += align256(bytes); return p; };

    unsigned* csr = (unsigned*)carve((size_t)MBN * CAPM * 4);   // 10.3 MB, live all passes
    // contiguous zero region: deg | acc1 | acc3 | acc2  (NN*19 words)
    char* zr = carve((size_t)NN * 19 * 4);                      // 7.6 MB
    int*   deg  = (int*)zr;
    float* acc1 = (float*)(zr + (size_t)NN * 4);
    float* acc3 = (float*)(zr + (size_t)NN * 8);
    float* acc2 = (float*)(zr + (size_t)NN * 12);
    unsigned* cursorA = (unsigned*)carve((size_t)MBN * 4);
    float* dis = (float*)carve((size_t)NN * 4);
    float* y1  = (float*)carve((size_t)NN * 4);
    float* y2  = (float*)carve((size_t)NN * 16 * 4);            // 6.4 MB
    float* y3  = (float*)carve((size_t)NN * 4);

    dim3 B(256);
    auto cdiv = [](int a, int b) { return (a + b - 1) / b; };
    int zq = NN * 19 / 4;

    kzero  <<<cdiv(zq, 256), B, 0, stream>>>((uint4*)zr, cursorA);
    kpartA <<<NPB, B, 0, stream>>>(src, dst, cursorA, csr);
    kdeg   <<<NAB, B, 0, stream>>>(csr, cursorA, deg);
    kdisy1 <<<cdiv(NN, 256), B, 0, stream>>>(deg, x, dis, y1);
    kaggs  <<<NAB, B, 0, stream>>>(csr, cursorA, y1, acc1);
    klin12 <<<NN * 16 / 256, B, 0, stream>>>(acc1, y1, dis, W1, b1, W2, y2);
    kagg16s<<<NAB, B, 0, stream>>>(csr, cursorA, y2, acc2);
    klin3  <<<NN * 16 / 256, B, 0, stream>>>(acc2, y2, dis, b2, W3, y3);
    kaggs  <<<NAB, B, 0, stream>>>(csr, cursorA, y3, acc3);
    kout   <<<cdiv(NN, 256), B, 0, stream>>>(acc3, y3, dis, b3, out);
}

// Round 13
// 119.775 us; speedup vs baseline: 2.9303x; 2.9303x over previous
//
#include <hip/hip_runtime.h>

static constexpr int NN   = 100000;
static constexpr int NE   = 2400000;
static constexpr int BSH  = 7;                     // fine bucket shift (128 nodes)
static constexpr int BSZ  = 128;                   // nodes per fine bucket
static constexpr int NB   = (NN + BSZ - 1) / BSZ;  // 782 fine buckets
static constexpr int MSH  = 9;                     // mid bucket shift (512 nodes)
static constexpr unsigned MMSK = 511;
static constexpr int MBN  = (NN + 511) / 512;      // 196 mid buckets
static constexpr int CAPM = 13184;                 // per-mid capacity (mean 12245 + ~8.5 sigma)
static constexpr int NPB  = 512;                   // partition blocks
static constexpr int SEG  = 4688;                  // edges per partition block (last ragged)
static constexpr int CAP  = 4224;                  // per-fine csr2 capacity (mean 3070 + 20 sigma)
static_assert((size_t)NPB * SEG >= NE, "segments cover edge list");
static_assert(MBN <= 256, "mid hist fits one pass");
static_assert(NN % 16 == 0, "16-lane-per-node kernels assume NN % 16 == 0");

// per-segment histogram over 196 mid buckets -> H[block][mid] (coalesced)
__global__ __launch_bounds__(256) void khistM(const int* __restrict__ dst,
                                              unsigned* __restrict__ H) {
    __shared__ unsigned h[MBN];
    int b = blockIdx.x, t = threadIdx.x;
    for (int k = t; k < MBN; k += 256) h[k] = 0;
    __syncthreads();
    int off = b * SEG;
    int n = NE - off; if (n > SEG) n = SEG;
    for (int j = t; j < n; j += 256)
        atomicAdd(&h[(unsigned)dst[off + j] >> MSH], 1u);
    __syncthreads();
    for (int k = t; k < MBN; k += 256) H[(size_t)b * MBN + k] = h[k];
}

// per-mid exclusive scan over the 512 blocks -> P[mid][block] (coalesced write)
__global__ __launch_bounds__(512) void kscanM(const unsigned* __restrict__ H,
                                              unsigned* __restrict__ P,
                                              unsigned* __restrict__ cntM) {
    __shared__ unsigned a[512], b2[512];
    int k = blockIdx.x, t = threadIdx.x;
    unsigned v = H[(size_t)t * MBN + k];   // strided read, H is L2-resident
    a[t] = v;
    __syncthreads();
    unsigned* cu = a; unsigned* nx = b2;
    for (int o = 1; o < 512; o <<= 1) {
        unsigned x = cu[t];
        if (t >= o) x += cu[t - o];
        nx[t] = x;
        __syncthreads();
        unsigned* tm = cu; cu = nx; nx = tm;
    }
    P[(size_t)k * NPB + t] = cu[t] - v;
    if (t == 511) cntM[k] = cu[t];
}

// direct scatter into 196 fixed-capacity mid regions. Open-line working set:
// 64 blocks/XCD * 196 lines * 64B = 0.8MB < 4MB L2 -> writes coalesce in L2.
__global__ __launch_bounds__(256) void kscatterM(const int* __restrict__ src,
                                                 const int* __restrict__ dst,
                                                 const unsigned* __restrict__ P,
                                                 unsigned* __restrict__ csr) {
    __shared__ unsigned lcur[MBN];
    int b = blockIdx.x, t = threadIdx.x;
    for (int k = t; k < MBN; k += 256)
        lcur[k] = (unsigned)k * CAPM + P[(size_t)k * NPB + b];
    __syncthreads();
    int off = b * SEG;
    int n = NE - off; if (n > SEG) n = SEG;
    for (int j = t; j < n; j += 256) {
        unsigned d = (unsigned)dst[off + j], s = (unsigned)src[off + j];
        unsigned pos = atomicAdd(&lcur[d >> MSH], 1u);
        csr[pos] = (s << MSH) | (d & MMSK);
    }
}

// fine bucket f filters its mid region (L2/L3-hot), LDS counting-sort by local
// node, writes csr2 into fixed-cap fine region; emits rstart/rcnt, dis, y1
__global__ __launch_bounds__(256) void kcsrB(const unsigned* __restrict__ csr,
                                             const unsigned* __restrict__ cntM,
                                             const float* __restrict__ x,
                                             unsigned* __restrict__ csr2,
                                             unsigned* __restrict__ rstart,
                                             unsigned* __restrict__ rcnt,
                                             float* __restrict__ dis,
                                             float* __restrict__ y1) {
    __shared__ unsigned codes[CAP];
    __shared__ unsigned sorted[CAP];
    __shared__ int cnt[BSZ];
    __shared__ int sa[BSZ], sb2[BSZ];
    __shared__ unsigned cur[BSZ];
    __shared__ unsigned top;
    int f = blockIdx.x, t = threadIdx.x;
    unsigned m = (unsigned)f >> 2, fl = (unsigned)f & 3;
    unsigned sbase = m * (unsigned)CAPM;
    unsigned nM = cntM[m]; if (nM > CAPM) nM = CAPM;
    if (t < BSZ) cnt[t] = 0;
    if (t == 0) top = 0;
    __syncthreads();
    for (unsigned j = t; j < nM; j += 256) {
        unsigned c = csr[sbase + j];
        unsigned loc = c & MMSK;
        if ((loc >> BSH) == fl) {
            atomicAdd(&cnt[loc & (BSZ - 1)], 1);
            unsigned p = atomicAdd(&top, 1u);
            if (p < CAP) codes[p] = c;
        }
    }
    __syncthreads();
    unsigned n = top; if (n > CAP) n = CAP;
    if (t < BSZ) sa[t] = cnt[t];
    __syncthreads();
    int* cp = sa; int* xs = sb2;
    for (int o = 1; o < BSZ; o <<= 1) {
        if (t < BSZ) { int v = cp[t]; if (t >= o) v += cp[t - o]; xs[t] = v; }
        __syncthreads();
        int* tm = cp; cp = xs; xs = tm;
    }
    unsigned s0 = (unsigned)f * CAP;
    int node = f * BSZ + t;
    if (t < BSZ) {
        int excl = cp[t] - cnt[t];
        cur[t] = (unsigned)excl;
        if (node < NN) {
            rstart[node] = s0 + (unsigned)excl;
            rcnt[node] = (unsigned)cnt[t];
            float d = rsqrtf((float)(cnt[t] + 1));
            dis[node] = d;
            y1[node] = d * x[node];
        }
    }
    __syncthreads();
    for (unsigned j = t; j < n; j += 256) {
        unsigned cc = codes[j];
        unsigned pos = atomicAdd(&cur[cc & (BSZ - 1)], 1u);
        sorted[pos] = cc >> MSH;       // src node id, grouped by dst node
    }
    __syncthreads();
    for (unsigned j = t; j < n; j += 256) csr2[s0 + j] = sorted[j];
}

// ---- aggregation phase (round-5/10 proven gather kernels) ----

__global__ __launch_bounds__(256) void kagg1lin(const unsigned* __restrict__ srcs,
                                                const unsigned* __restrict__ rstart,
                                                const unsigned* __restrict__ rcnt,
                                                const float* __restrict__ y1,
                                                const float* __restrict__ dis,
                                                const float* __restrict__ W1,
                                                const float* __restrict__ b1,
                                                const float* __restrict__ W2,
                                                float* __restrict__ y2) {
    __shared__ float sW1[32], sb1[32], sW2[512];
    int t = threadIdx.x;
    if (t < 32) { sW1[t] = W1[t]; sb1[t] = b1[t]; }
    for (int i = t; i < 512; i += 256) sW2[i] = W2[i];
    __syncthreads();
    int node = blockIdx.x * 16 + (t >> 4);
    int g = t & 15;
    unsigned r0 = rstart[node], r1 = r0 + rcnt[node];
    float s0 = 0.f, s1 = 0.f;
    unsigned j = r0 + g;
    for (; j + 16 < r1; j += 32) {
        unsigned i0 = srcs[j], i1 = srcs[j + 16];
        float v0 = y1[i0], v1 = y1[i1];
        s0 += v0; s1 += v1;
    }
    if (j < r1) s0 += y1[srcs[j]];
    float sum = s0 + s1;
    sum += __shfl_xor(sum, 1, 16);
    sum += __shfl_xor(sum, 2, 16);
    sum += __shfl_xor(sum, 4, 16);
    sum += __shfl_xor(sum, 8, 16);          // all 16 lanes hold the total
    float d = dis[node];
    float a = d * (sum + y1[node]);
    float acc = 0.f;
#pragma unroll
    for (int f = 0; f < 32; ++f) {
        float h = fmaxf(a * sW1[f] + sb1[f], 0.f);
        acc += h * sW2[f * 16 + g];
    }
    y2[(size_t)node * 16 + g] = d * acc;
}

__global__ __launch_bounds__(256) void kagg16g(const unsigned* __restrict__ srcs,
                                               const unsigned* __restrict__ rstart,
                                               const unsigned* __restrict__ rcnt,
                                               const float* __restrict__ y2,
                                               const float* __restrict__ dis,
                                               const float* __restrict__ b2,
                                               const float* __restrict__ W3,
                                               float* __restrict__ y3) {
    int t = threadIdx.x;
    int node = blockIdx.x * 16 + (t >> 4);
    int g = t & 15;
    unsigned r0 = rstart[node], r1 = r0 + rcnt[node];
    const float* yg = y2 + g;
    float s0 = 0.f, s1 = 0.f, s2 = 0.f, s3 = 0.f;
    unsigned j = r0;
    for (; j + 8 <= r1; j += 8) {
        unsigned i0 = srcs[j + 0], i1 = srcs[j + 1], i2 = srcs[j + 2], i3 = srcs[j + 3];
        unsigned i4 = srcs[j + 4], i5 = srcs[j + 5], i6 = srcs[j + 6], i7 = srcs[j + 7];
        float v0 = yg[(size_t)i0 * 16], v1 = yg[(size_t)i1 * 16];
        float v2 = yg[(size_t)i2 * 16], v3 = yg[(size_t)i3 * 16];
        float v4 = yg[(size_t)i4 * 16], v5 = yg[(size_t)i5 * 16];
        float v6 = yg[(size_t)i6 * 16], v7 = yg[(size_t)i7 * 16];
        s0 += v0; s1 += v1; s2 += v2; s3 += v3;
        s0 += v4; s1 += v5; s2 += v6; s3 += v7;
    }
    for (; j + 2 <= r1; j += 2) {
        unsigned i0 = srcs[j], i1 = srcs[j + 1];
        float v0 = yg[(size_t)i0 * 16], v1 = yg[(size_t)i1 * 16];
        s0 += v0; s1 += v1;
    }
    if (j < r1) s2 += yg[(size_t)srcs[j] * 16];
    float sum = (s0 + s1) + (s2 + s3);
    float d = dis[node];
    float a2 = d * (sum + y2[(size_t)node * 16 + g]) + b2[g];
    float hg = fmaxf(a2, 0.f) * W3[g];
    hg += __shfl_xor(hg, 1, 16);
    hg += __shfl_xor(hg, 2, 16);
    hg += __shfl_xor(hg, 4, 16);
    hg += __shfl_xor(hg, 8, 16);
    if (g == 0) y3[node] = d * hg;
}

__global__ __launch_bounds__(256) void kaggsg(const unsigned* __restrict__ srcs,
                                              const unsigned* __restrict__ rstart,
                                              const unsigned* __restrict__ rcnt,
                                              const float* __restrict__ y,
                                              const float* __restrict__ dis,
                                              float* __restrict__ out,
                                              const float* __restrict__ bias) {
    int t = threadIdx.x;
    int node = blockIdx.x * 16 + (t >> 4);
    int g = t & 15;
    unsigned r0 = rstart[node], r1 = r0 + rcnt[node];
    float s0 = 0.f, s1 = 0.f;
    unsigned j = r0 + g;
    for (; j + 16 < r1; j += 32) {
        unsigned i0 = srcs[j], i1 = srcs[j + 16];
        float v0 = y[i0], v1 = y[i1];
        s0 += v0; s1 += v1;
    }
    if (j < r1) s0 += y[srcs[j]];
    float sum = s0 + s1;
    sum += __shfl_xor(sum, 1, 16);
    sum += __shfl_xor(sum, 2, 16);
    sum += __shfl_xor(sum, 4, 16);
    sum += __shfl_xor(sum, 8, 16);
    if (g == 0) {
        float d = dis[node];
        out[node] = d * (sum + y[node]) + (bias ? bias[0] : 0.f);
    }
}

extern "C" void kernel_launch(void* const* d_in, const int* in_sizes, int n_in,
                              void* d_out, int out_size, void* d_ws, size_t ws_size,
                              hipStream_t stream) {
    const float* x  = (const float*)d_in[0];
    const int*   ei = (const int*)d_in[1];
    const int* src = ei;
    const int* dst = ei + NE;
    const float* W1 = (const float*)d_in[2];
    const float* b1 = (const float*)d_in[3];
    const float* W2 = (const float*)d_in[4];
    const float* b2 = (const float*)d_in[5];
    const float* W3 = (const float*)d_in[6];
    const float* b3 = (const float*)d_in[7];
    float* out = (float*)d_out;

    auto align256 = [](size_t v) { return (v + 255) & ~(size_t)255; };
    char* w = (char*)d_ws;
    auto carve = [&](size_t bytes) { char* p = w; w += align256(bytes); return p; };

    // region A: mid-bucket regions (dead after kcsrB) -> reused as y2
    size_t regA_sz = (size_t)MBN * CAPM * 4;                    // 10.3 MB
    if (regA_sz < (size_t)NN * 16 * 4) regA_sz = (size_t)NN * 16 * 4;
    char* regA = carve(regA_sz);
    unsigned* csr = (unsigned*)regA;
    float*    y2  = (float*)regA;
    unsigned* csr2   = (unsigned*)carve((size_t)NB * CAP * 4);  // 13.2 MB
    unsigned* H      = (unsigned*)carve((size_t)NPB * MBN * 4); // 400 KB
    unsigned* P      = (unsigned*)carve((size_t)MBN * NPB * 4); // 400 KB
    unsigned* cntM   = (unsigned*)carve((size_t)MBN * 4);
    unsigned* rstart = (unsigned*)carve((size_t)NN * 4);
    unsigned* rcnt   = (unsigned*)carve((size_t)NN * 4);
    float*    dis    = (float*)   carve((size_t)NN * 4);
    float*    y1     = (float*)   carve((size_t)NN * 4);
    float*    y3     = (float*)   carve((size_t)NN * 4);

    dim3 B(256);

    // partition: mid hist -> deterministic P scan -> direct mid scatter -> fine sort
    khistM   <<<NPB, B, 0, stream>>>(dst, H);
    kscanM   <<<MBN, dim3(512), 0, stream>>>(H, P, cntM);
    kscatterM<<<NPB, B, 0, stream>>>(src, dst, P, csr);
    kcsrB    <<<NB, B, 0, stream>>>(csr, cntM, x, csr2, rstart, rcnt, dis, y1);

    // layer 1 aggregate + dense 1->32->16 -> y2 = dis*h2pre
    kagg1lin<<<NN / 16, B, 0, stream>>>(csr2, rstart, rcnt, y1, dis, W1, b1, W2, y2);

    // layer 2 aggregate (16-wide) fused with layer-3 linear -> y3
    kagg16g <<<NN / 16, B, 0, stream>>>(csr2, rstart, rcnt, y2, dis, b2, W3, y3);

    // layer 3 aggregate (scalar) -> out
    kaggsg  <<<NN / 16, B, 0, stream>>>(csr2, rstart, rcnt, y3, dis, out, b3);
}

// Round 14
// 112.409 us; speedup vs baseline: 3.1223x; 1.0655x over previous
//
#include <hip/hip_runtime.h>
#include <hip/hip_fp16.h>

static constexpr int NN   = 100000;
static constexpr int NE   = 2400000;
static constexpr int BSH  = 7;                     // fine bucket shift (128 nodes)
static constexpr int BSZ  = 128;                   // nodes per fine bucket
static constexpr int NB   = (NN + BSZ - 1) / BSZ;  // 782 fine buckets
static constexpr int MSH  = 9;                     // mid bucket shift (512 nodes)
static constexpr unsigned MMSK = 511;
static constexpr int MBN  = (NN + 511) / 512;      // 196 mid buckets
static constexpr int CAPM = 13184;                 // per-mid capacity (mean 12245 + ~8.5 sigma)
static constexpr int NPB  = 512;                   // partition blocks
static constexpr int SEG  = 4688;                  // edges per partition block (last ragged)
static constexpr int CAP  = 4224;                  // per-fine csr2 capacity (mean 3070 + 20 sigma)
static_assert((size_t)NPB * SEG >= NE, "segments cover edge list");
static_assert(MBN <= 256, "mid hist fits one pass");
static_assert(NN % 16 == 0, "16-lane-per-node kernels assume NN % 16 == 0");

// per-segment histogram over 196 mid buckets -> H[block][mid] (coalesced)
__global__ __launch_bounds__(256) void khistM(const int* __restrict__ dst,
                                              unsigned* __restrict__ H) {
    __shared__ unsigned h[MBN];
    int b = blockIdx.x, t = threadIdx.x;
    for (int k = t; k < MBN; k += 256) h[k] = 0;
    __syncthreads();
    int off = b * SEG;
    int n = NE - off; if (n > SEG) n = SEG;
    for (int j = t; j < n; j += 256)
        atomicAdd(&h[(unsigned)dst[off + j] >> MSH], 1u);
    __syncthreads();
    for (int k = t; k < MBN; k += 256) H[(size_t)b * MBN + k] = h[k];
}

// per-mid exclusive scan over the 512 blocks -> P[mid][block] (coalesced write)
__global__ __launch_bounds__(512) void kscanM(const unsigned* __restrict__ H,
                                              unsigned* __restrict__ P,
                                              unsigned* __restrict__ cntM) {
    __shared__ unsigned a[512], b2[512];
    int k = blockIdx.x, t = threadIdx.x;
    unsigned v = H[(size_t)t * MBN + k];   // strided read, H is L2-resident
    a[t] = v;
    __syncthreads();
    unsigned* cu = a; unsigned* nx = b2;
    for (int o = 1; o < 512; o <<= 1) {
        unsigned x = cu[t];
        if (t >= o) x += cu[t - o];
        nx[t] = x;
        __syncthreads();
        unsigned* tm = cu; cu = nx; nx = tm;
    }
    P[(size_t)k * NPB + t] = cu[t] - v;
    if (t == 511) cntM[k] = cu[t];
}

// direct scatter into 196 fixed-capacity mid regions. Open-line working set:
// 64 blocks/XCD * 196 lines * 64B = 0.8MB < 4MB L2 -> writes coalesce in L2.
__global__ __launch_bounds__(256) void kscatterM(const int* __restrict__ src,
                                                 const int* __restrict__ dst,
                                                 const unsigned* __restrict__ P,
                                                 unsigned* __restrict__ csr) {
    __shared__ unsigned lcur[MBN];
    int b = blockIdx.x, t = threadIdx.x;
    for (int k = t; k < MBN; k += 256)
        lcur[k] = (unsigned)k * CAPM + P[(size_t)k * NPB + b];
    __syncthreads();
    int off = b * SEG;
    int n = NE - off; if (n > SEG) n = SEG;
    for (int j = t; j < n; j += 256) {
        unsigned d = (unsigned)dst[off + j], s = (unsigned)src[off + j];
        unsigned pos = atomicAdd(&lcur[d >> MSH], 1u);
        csr[pos] = (s << MSH) | (d & MMSK);
    }
}

// fine bucket f filters its mid region (L2/L3-hot), LDS counting-sort by local
// node, writes csr2 into fixed-cap fine region; emits rstart/rcnt, dis, y1
__global__ __launch_bounds__(256) void kcsrB(const unsigned* __restrict__ csr,
                                             const unsigned* __restrict__ cntM,
                                             const float* __restrict__ x,
                                             unsigned* __restrict__ csr2,
                                             unsigned* __restrict__ rstart,
                                             unsigned* __restrict__ rcnt,
                                             float* __restrict__ dis,
                                             float* __restrict__ y1) {
    __shared__ unsigned codes[CAP];
    __shared__ unsigned sorted[CAP];
    __shared__ int cnt[BSZ];
    __shared__ int sa[BSZ], sb2[BSZ];
    __shared__ unsigned cur[BSZ];
    __shared__ unsigned top;
    int f = blockIdx.x, t = threadIdx.x;
    unsigned m = (unsigned)f >> 2, fl = (unsigned)f & 3;
    unsigned sbase = m * (unsigned)CAPM;
    unsigned nM = cntM[m]; if (nM > CAPM) nM = CAPM;
    if (t < BSZ) cnt[t] = 0;
    if (t == 0) top = 0;
    __syncthreads();
    for (unsigned j = t; j < nM; j += 256) {
        unsigned c = csr[sbase + j];
        unsigned loc = c & MMSK;
        if ((loc >> BSH) == fl) {
            atomicAdd(&cnt[loc & (BSZ - 1)], 1);
            unsigned p = atomicAdd(&top, 1u);
            if (p < CAP) codes[p] = c;
        }
    }
    __syncthreads();
    unsigned n = top; if (n > CAP) n = CAP;
    if (t < BSZ) sa[t] = cnt[t];
    __syncthreads();
    int* cp = sa; int* xs = sb2;
    for (int o = 1; o < BSZ; o <<= 1) {
        if (t < BSZ) { int v = cp[t]; if (t >= o) v += cp[t - o]; xs[t] = v; }
        __syncthreads();
        int* tm = cp; cp = xs; xs = tm;
    }
    unsigned s0 = (unsigned)f * CAP;
    int node = f * BSZ + t;
    if (t < BSZ) {
        int excl = cp[t] - cnt[t];
        cur[t] = (unsigned)excl;
        if (node < NN) {
            rstart[node] = s0 + (unsigned)excl;
            rcnt[node] = (unsigned)cnt[t];
            float d = rsqrtf((float)(cnt[t] + 1));
            dis[node] = d;
            y1[node] = d * x[node];
        }
    }
    __syncthreads();
    for (unsigned j = t; j < n; j += 256) {
        unsigned cc = codes[j];
        unsigned pos = atomicAdd(&cur[cc & (BSZ - 1)], 1u);
        sorted[pos] = cc >> MSH;       // src node id, grouped by dst node
    }
    __syncthreads();
    for (unsigned j = t; j < n; j += 256) csr2[s0 + j] = sorted[j];
}

// ---- aggregation phase ----

// layer-1 aggregate + dense 1->32->16; y2 stored as fp16 (3.2MB -> L2-resident)
__global__ __launch_bounds__(256) void kagg1lin(const unsigned* __restrict__ srcs,
                                                const unsigned* __restrict__ rstart,
                                                const unsigned* __restrict__ rcnt,
                                                const float* __restrict__ y1,
                                                const float* __restrict__ dis,
                                                const float* __restrict__ W1,
                                                const float* __restrict__ b1,
                                                const float* __restrict__ W2,
                                                __half* __restrict__ y2) {
    __shared__ float sW1[32], sb1[32], sW2[512];
    int t = threadIdx.x;
    if (t < 32) { sW1[t] = W1[t]; sb1[t] = b1[t]; }
    for (int i = t; i < 512; i += 256) sW2[i] = W2[i];
    __syncthreads();
    int node = blockIdx.x * 16 + (t >> 4);
    int g = t & 15;
    unsigned r0 = rstart[node], r1 = r0 + rcnt[node];
    float s0 = 0.f, s1 = 0.f;
    unsigned j = r0 + g;
    for (; j + 16 < r1; j += 32) {
        unsigned i0 = srcs[j], i1 = srcs[j + 16];
        float v0 = y1[i0], v1 = y1[i1];
        s0 += v0; s1 += v1;
    }
    if (j < r1) s0 += y1[srcs[j]];
    float sum = s0 + s1;
    sum += __shfl_xor(sum, 1, 16);
    sum += __shfl_xor(sum, 2, 16);
    sum += __shfl_xor(sum, 4, 16);
    sum += __shfl_xor(sum, 8, 16);          // all 16 lanes hold the total
    float d = dis[node];
    float a = d * (sum + y1[node]);
    float acc = 0.f;
#pragma unroll
    for (int f = 0; f < 32; ++f) {
        float h = fmaxf(a * sW1[f] + sb1[f], 0.f);
        acc += h * sW2[f * 16 + g];
    }
    y2[(size_t)node * 16 + g] = __float2half(d * acc);
}

// 16-wide gather aggregate fused with layer-3 linear. y2 is fp16 and
// L2-resident per XCD -> random row gathers become L2 hits.
__global__ __launch_bounds__(256) void kagg16g(const unsigned* __restrict__ srcs,
                                               const unsigned* __restrict__ rstart,
                                               const unsigned* __restrict__ rcnt,
                                               const __half* __restrict__ y2,
                                               const float* __restrict__ dis,
                                               const float* __restrict__ b2,
                                               const float* __restrict__ W3,
                                               float* __restrict__ y3) {
    int t = threadIdx.x;
    int node = blockIdx.x * 16 + (t >> 4);
    int g = t & 15;
    unsigned r0 = rstart[node], r1 = r0 + rcnt[node];
    const __half* yg = y2 + g;
    float s0 = 0.f, s1 = 0.f, s2 = 0.f, s3 = 0.f;
    unsigned j = r0;
    for (; j + 8 <= r1; j += 8) {
        unsigned i0 = srcs[j + 0], i1 = srcs[j + 1], i2 = srcs[j + 2], i3 = srcs[j + 3];
        unsigned i4 = srcs[j + 4], i5 = srcs[j + 5], i6 = srcs[j + 6], i7 = srcs[j + 7];
        float v0 = __half2float(yg[(size_t)i0 * 16]);
        float v1 = __half2float(yg[(size_t)i1 * 16]);
        float v2 = __half2float(yg[(size_t)i2 * 16]);
        float v3 = __half2float(yg[(size_t)i3 * 16]);
        float v4 = __half2float(yg[(size_t)i4 * 16]);
        float v5 = __half2float(yg[(size_t)i5 * 16]);
        float v6 = __half2float(yg[(size_t)i6 * 16]);
        float v7 = __half2float(yg[(size_t)i7 * 16]);
        s0 += v0; s1 += v1; s2 += v2; s3 += v3;
        s0 += v4; s1 += v5; s2 += v6; s3 += v7;
    }
    for (; j + 2 <= r1; j += 2) {
        unsigned i0 = srcs[j], i1 = srcs[j + 1];
        s0 += __half2float(yg[(size_t)i0 * 16]);
        s1 += __half2float(yg[(size_t)i1 * 16]);
    }
    if (j < r1) s2 += __half2float(yg[(size_t)srcs[j] * 16]);
    float sum = (s0 + s1) + (s2 + s3);
    float d = dis[node];
    float a2 = d * (sum + __half2float(y2[(size_t)node * 16 + g])) + b2[g];
    float hg = fmaxf(a2, 0.f) * W3[g];
    hg += __shfl_xor(hg, 1, 16);
    hg += __shfl_xor(hg, 2, 16);
    hg += __shfl_xor(hg, 4, 16);
    hg += __shfl_xor(hg, 8, 16);
    if (g == 0) y3[node] = d * hg;
}

__global__ __launch_bounds__(256) void kaggsg(const unsigned* __restrict__ srcs,
                                              const unsigned* __restrict__ rstart,
                                              const unsigned* __restrict__ rcnt,
                                              const float* __restrict__ y,
                                              const float* __restrict__ dis,
                                              float* __restrict__ out,
                                              const float* __restrict__ bias) {
    int t = threadIdx.x;
    int node = blockIdx.x * 16 + (t >> 4);
    int g = t & 15;
    unsigned r0 = rstart[node], r1 = r0 + rcnt[node];
    float s0 = 0.f, s1 = 0.f;
    unsigned j = r0 + g;
    for (; j + 16 < r1; j += 32) {
        unsigned i0 = srcs[j], i1 = srcs[j + 16];
        float v0 = y[i0], v1 = y[i1];
        s0 += v0; s1 += v1;
    }
    if (j < r1) s0 += y[srcs[j]];
    float sum = s0 + s1;
    sum += __shfl_xor(sum, 1, 16);
    sum += __shfl_xor(sum, 2, 16);
    sum += __shfl_xor(sum, 4, 16);
    sum += __shfl_xor(sum, 8, 16);
    if (g == 0) {
        float d = dis[node];
        out[node] = d * (sum + y[node]) + (bias ? bias[0] : 0.f);
    }
}

extern "C" void kernel_launch(void* const* d_in, const int* in_sizes, int n_in,
                              void* d_out, int out_size, void* d_ws, size_t ws_size,
                              hipStream_t stream) {
    const float* x  = (const float*)d_in[0];
    const int*   ei = (const int*)d_in[1];
    const int* src = ei;
    const int* dst = ei + NE;
    const float* W1 = (const float*)d_in[2];
    const float* b1 = (const float*)d_in[3];
    const float* W2 = (const float*)d_in[4];
    const float* b2 = (const float*)d_in[5];
    const float* W3 = (const float*)d_in[6];
    const float* b3 = (const float*)d_in[7];
    float* out = (float*)d_out;

    auto align256 = [](size_t v) { return (v + 255) & ~(size_t)255; };
    char* w = (char*)d_ws;
    auto carve = [&](size_t bytes) { char* p = w; w += align256(bytes); return p; };

    // region A: mid-bucket regions (dead after kcsrB) -> reused as fp16 y2
    size_t regA_sz = (size_t)MBN * CAPM * 4;                    // 10.3 MB
    char* regA = carve(regA_sz);
    unsigned* csr = (unsigned*)regA;
    __half*   y2  = (__half*)regA;                              // 3.2 MB used
    unsigned* csr2   = (unsigned*)carve((size_t)NB * CAP * 4);  // 13.2 MB
    unsigned* H      = (unsigned*)carve((size_t)NPB * MBN * 4); // 400 KB
    unsigned* P      = (unsigned*)carve((size_t)MBN * NPB * 4); // 400 KB
    unsigned* cntM   = (unsigned*)carve((size_t)MBN * 4);
    unsigned* rstart = (unsigned*)carve((size_t)NN * 4);
    unsigned* rcnt   = (unsigned*)carve((size_t)NN * 4);
    float*    dis    = (float*)   carve((size_t)NN * 4);
    float*    y1     = (float*)   carve((size_t)NN * 4);
    float*    y3     = (float*)   carve((size_t)NN * 4);

    dim3 B(256);

    // partition: mid hist -> deterministic P scan -> direct mid scatter -> fine sort
    khistM   <<<NPB, B, 0, stream>>>(dst, H);
    kscanM   <<<MBN, dim3(512), 0, stream>>>(H, P, cntM);
    kscatterM<<<NPB, B, 0, stream>>>(src, dst, P, csr);
    kcsrB    <<<NB, B, 0, stream>>>(csr, cntM, x, csr2, rstart, rcnt, dis, y1);

    // layer 1 aggregate + dense 1->32->16 -> y2 (fp16) = dis*h2pre
    kagg1lin<<<NN / 16, B, 0, stream>>>(csr2, rstart, rcnt, y1, dis, W1, b1, W2, y2);

    // layer 2 aggregate (16-wide, fp16 L2-resident gathers) + layer-3 linear -> y3
    kagg16g <<<NN / 16, B, 0, stream>>>(csr2, rstart, rcnt, y2, dis, b2, W3, y3);

    // layer 3 aggregate (scalar) -> out
    kaggsg  <<<NN / 16, B, 0, stream>>>(csr2, rstart, rcnt, y3, dis, out, b3);
}